// Round 2
// 277.089 us; speedup vs baseline: 1.0102x; 1.0102x over previous
//
#include <hip/hip_runtime.h>

#define BB 8
#define HH 512
#define WW 512
#define K2 9
#define HW (HH * WW)

// Tile geometry: each block computes a TY x TX pixel tile.
// LDS stages depth rows [ty0-5, ty0+TY+5] x cols [tx0-5, tx0+TX+5]
// (halo covers |offset| <= 4; rare tail falls back to global).
#define TX 64
#define TY 16
#define NROWS (TY + 11)   // 27
#define NCOLS (TX + 11)   // 75
// STRIDE 77: odd multiplier vs 32 banks (77 mod 32 = 13) so the 4 row-groups
// of a wave (and +/-1 row jitter from dy) scatter across odd AND even banks.
// Old 76 (mod 32 = 12, even) pinned all groups to the even-bank set -> 4-way.
#define STRIDE 77
#define NSTAGE 8          // ceil(NROWS*NCOLS / 256) = ceil(2025/256)

// Global fallback with reference clamp+mask semantics (rare path).
__device__ __noinline__ float gsample(const float* __restrict__ dimg,
                                      float py, float px) {
    const float y0f = floorf(py);
    const float x0f = floorf(px);
    const float ty = py - y0f;
    const float tx = px - x0f;
    const int y0 = (int)y0f, x0 = (int)x0f;
    const int y1 = y0 + 1,   x1 = x0 + 1;
    const int y0c = min(max(y0, 0), HH - 1);
    const int y1c = min(max(y1, 0), HH - 1);
    const int x0c = min(max(x0, 0), WW - 1);
    const int x1c = min(max(x1, 0), WW - 1);
    const float v00 = dimg[y0c * WW + x0c];
    const float v01 = dimg[y0c * WW + x1c];
    const float v10 = dimg[y1c * WW + x0c];
    const float v11 = dimg[y1c * WW + x1c];
    const bool vy0 = (unsigned)y0 < HH, vy1 = (unsigned)y1 < HH;
    const bool vx0 = (unsigned)x0 < WW, vx1 = (unsigned)x1 < WW;
    const float w00 = (vy0 & vx0) ? (1.f - ty) * (1.f - tx) : 0.f;
    const float w01 = (vy0 & vx1) ? (1.f - ty) * tx         : 0.f;
    const float w10 = (vy1 & vx0) ? ty * (1.f - tx)         : 0.f;
    const float w11 = (vy1 & vx1) ? ty * tx                 : 0.f;
    return v00 * w00 + v01 * w01 + v10 * w10 + v11 * w11;
}

// One batch = 3 k-taps worth of weight/offset float4s (9 loads, 36 VGPRs).
struct B3 { float4 w0, w1, w2, dy0, dy1, dy2, dx0, dx1, dx2; };

template<int KB>
__device__ __forceinline__ void load_b3(B3& r,
                                        const float* __restrict__ wp,
                                        const float* __restrict__ op) {
    r.dy0 = *(const float4*)(op + (2 * (KB + 0)    ) * HW);
    r.dx0 = *(const float4*)(op + (2 * (KB + 0) + 1) * HW);
    r.dy1 = *(const float4*)(op + (2 * (KB + 1)    ) * HW);
    r.dx1 = *(const float4*)(op + (2 * (KB + 1) + 1) * HW);
    r.dy2 = *(const float4*)(op + (2 * (KB + 2)    ) * HW);
    r.dx2 = *(const float4*)(op + (2 * (KB + 2) + 1) * HW);
    r.w0  = *(const float4*)(wp + (KB + 0) * HW);
    r.w1  = *(const float4*)(wp + (KB + 1) * HW);
    r.w2  = *(const float4*)(wp + (KB + 2) * HW);
}

// Bilinear sample of one pixel (compile-time-unrolled j); hot path from LDS.
#define SAMPLE(dyv, dxv, xoff, sj)                                          \
    do {                                                                    \
        const float py = (dyv) + ybase;                                     \
        const float px = (dxv) + xbase + (float)(xoff);                     \
        const float y0f = floorf(py);                                       \
        const float x0f = floorf(px);                                       \
        const float fty = py - y0f;                                         \
        const float ftx = px - x0f;                                         \
        const int iy = (int)y0f - ry0;                                      \
        const int ix = (int)x0f - cx0;                                      \
        if ((unsigned)iy < NROWS - 1 && (unsigned)ix < NCOLS - 1) {         \
            const float* q = tile + iy * STRIDE + ix;                       \
            const float v00 = q[0], v01 = q[1];                             \
            const float v10 = q[STRIDE], v11 = q[STRIDE + 1];               \
            const float a0 = v00 + ftx * (v01 - v00);                       \
            const float a1 = v10 + ftx * (v11 - v10);                       \
            sj = a0 + fty * (a1 - a0);                                      \
        } else {                                                            \
            sj = gsample(dimg, py, px);                                     \
        }                                                                   \
    } while (0)

// One k-tap: 4 samples + accumulate. k order preserved (0..8) so the
// floating-point result is bit-identical to the previous kernel.
#define DO_K(K, w4, dy4, dx4)                                               \
    do {                                                                    \
        const float ybase = (float)(y - 1 + (K) / 3);                       \
        const float xbase = (float)(x - 1 + (K) % 3);                       \
        float s0, s1, s2, s3;                                               \
        SAMPLE((dy4).x, (dx4).x, 0, s0);                                    \
        SAMPLE((dy4).y, (dx4).y, 1, s1);                                    \
        SAMPLE((dy4).z, (dx4).z, 2, s2);                                    \
        SAMPLE((dy4).w, (dx4).w, 3, s3);                                    \
        accw.x += s0 * (w4).x;  accs.x += s0;  wsum.x += (w4).x;            \
        accw.y += s1 * (w4).y;  accs.y += s1;  wsum.y += (w4).y;            \
        accw.z += s2 * (w4).z;  accs.z += s2;  wsum.z += (w4).z;            \
        accw.w += s3 * (w4).w;  accs.w += s3;  wsum.w += (w4).w;            \
    } while (0)

// 128-VGPR class (4 waves/SIMD): room for 2 in-flight B3 batches (72 VGPR)
// of global loads -> the memory-level parallelism the 64-VGPR build lacked.
__global__ __launch_bounds__(256, 4) void pp_deconv_kernel(
    const float* __restrict__ depth,   // (B,1,H,W)
    const float* __restrict__ weight,  // (B,K2,H,W)
    const float* __restrict__ offset,  // (B,2*K2,H,W)
    float* __restrict__ out)           // (B,1,H,W)
{
    __shared__ float tile[NROWS * STRIDE];

    const int tid = threadIdx.x;
    const int tx0 = blockIdx.x * TX;
    const int ty0 = blockIdx.y * TY;
    const int b   = blockIdx.z;

    const int ry0 = ty0 - 5;   // global row of tile row 0
    const int cx0 = tx0 - 5;   // global col of tile col 0

    const float* dimg = depth + (size_t)b * HW;

    // ---- staging phase 1: issue ALL depth-tile loads into registers ----
    // (split from the LDS writes so the 8 loads pipeline back-to-back and
    //  the weight/offset prefetch below can issue before any waitcnt)
    float sv[NSTAGE];
    int   sa[NSTAGE];
#pragma unroll
    for (int u = 0; u < NSTAGE; ++u) {
        const int li = tid + u * 256;
        float v = 0.f;
        int   a = -1;
        if (li < NROWS * NCOLS) {
            const int r  = li / NCOLS;
            const int c  = li - r * NCOLS;
            const int gy = ry0 + r;
            const int gx = cx0 + c;
            if ((unsigned)gy < HH && (unsigned)gx < WW) v = dimg[gy * WW + gx];
            a = r * STRIDE + c;
        }
        sv[u] = v;
        sa[u] = a;
    }

    // ---- pixel mapping: 4 x-consecutive pixels per thread ----
    const int xl = (tid & 15) << 2;   // 0..60
    const int yl = tid >> 4;          // 0..15
    const int x = tx0 + xl;
    const int y = ty0 + yl;
    const int p = y * WW + x;

    const float* wp = weight + (size_t)b * K2 * HW + p;
    const float* op = offset + (size_t)b * 2 * K2 * HW + p;

    // ---- prefetch k=0..5 (18 float4 loads) BEFORE LDS writes/barrier:
    // no LDS dependency, so their latency hides under staging + barrier.
    B3 A, Bq;
    load_b3<0>(A, wp, op);
    load_b3<3>(Bq, wp, op);

    // ---- staging phase 2: LDS writes (waitcnt only reaches staging loads,
    // leaving the 18 prefetch loads in flight across the barrier) ----
#pragma unroll
    for (int u = 0; u < NSTAGE; ++u)
        if (sa[u] >= 0) tile[sa[u]] = sv[u];
    __syncthreads();

    float4 accw = make_float4(0.f, 0.f, 0.f, 0.f);
    float4 accs = make_float4(0.f, 0.f, 0.f, 0.f);
    float4 wsum = make_float4(0.f, 0.f, 0.f, 0.f);

    // ---- batch 0 compute (k=0..2) ----
    DO_K(0, A.w0, A.dy0, A.dx0);
    DO_K(1, A.w1, A.dy1, A.dx1);
    DO_K(2, A.w2, A.dy2, A.dx2);

    // ---- prefetch k=6..8 while batch 1 computes ----
    B3 C;
    load_b3<6>(C, wp, op);

    // ---- batch 1 compute (k=3..5) ----
    DO_K(3, Bq.w0, Bq.dy0, Bq.dx0);
    DO_K(4, Bq.w1, Bq.dy1, Bq.dx1);
    DO_K(5, Bq.w2, Bq.dy2, Bq.dx2);

    // ---- batch 2 compute (k=6..8) ----
    DO_K(6, C.w0, C.dy0, C.dx0);
    DO_K(7, C.w1, C.dy1, C.dx1);
    DO_K(8, C.w2, C.dy2, C.dx2);

    // residual depth from LDS (always in-tile, in-image)
    const float* dq = tile + (yl + 5) * STRIDE + (xl + 5);
    const float c9 = 1.0f / 9.0f;
    float4 o;
    o.x = accw.x - wsum.x * c9 * accs.x + dq[0];
    o.y = accw.y - wsum.y * c9 * accs.y + dq[1];
    o.z = accw.z - wsum.z * c9 * accs.z + dq[2];
    o.w = accw.w - wsum.w * c9 * accs.w + dq[3];
    *(float4*)(out + (size_t)b * HW + p) = o;
}

extern "C" void kernel_launch(void* const* d_in, const int* in_sizes, int n_in,
                              void* d_out, int out_size, void* d_ws, size_t ws_size,
                              hipStream_t stream) {
    const float* depth  = (const float*)d_in[0];
    const float* weight = (const float*)d_in[1];
    const float* offset = (const float*)d_in[2];
    float* out = (float*)d_out;

    dim3 grid(WW / TX, HH / TY, BB);   // 8 x 32 x 8 = 2048 blocks
    dim3 block(256);
    pp_deconv_kernel<<<grid, block, 0, stream>>>(depth, weight, offset, out);
}